// Round 5
// baseline (920.531 us; speedup 1.0000x reference)
//
#include <hip/hip_runtime.h>

#define NTAG 48
#define SEQ 1024
#define NBATCH 512

// broadcast lane `lane`'s value of v to all lanes (compile-time lane -> v_readlane imm)
__device__ __forceinline__ float rl_f32(float v, int lane) {
    return __int_as_float(__builtin_amdgcn_readlane(__float_as_int(v), lane));
}

// guaranteed single-instruction 3-input max (exact; max has no rounding)
__device__ __forceinline__ float max3(float a, float b, float c) {
    float d;
    asm("v_max3_f32 %0, %1, %2, %3" : "=v"(d) : "v"(a), "v"(b), "v"(c));
    return d;
}

__global__ __launch_bounds__(64, 1) void crf_viterbi_kernel(
    const float* __restrict__ em,      // [B, S, T]
    const float* __restrict__ trans,   // [T, T]
    const float* __restrict__ start,   // [T]
    const float* __restrict__ endt,    // [T]
    int* __restrict__ out,             // [B, S]  (tags, int32 — reference output dtype)
    unsigned char* __restrict__ bp)    // [B, S, T] backpointers (t=1..S-1)
{
    const int b  = blockIdx.x;
    const int j  = threadIdx.x;                 // 0..63; tags 0..47 valid
    const int jj = (j < NTAG) ? j : (NTAG - 1); // clamped for safe loads

    __shared__ int obuf[SEQ];

    // preload transition column j: trg[i] = T[i][j]
    float trg[NTAG];
#pragma unroll
    for (int i = 0; i < NTAG; ++i) trg[i] = trans[i * NTAG + jj];

    const float* emb = em + (size_t)b * SEQ * NTAG;
    unsigned char* bpb = bp + (size_t)b * SEQ * NTAG;

    float score = start[jj] + emb[jj];

    // software-prefetch emissions TWO steps ahead (HBM-miss latency ~900cyc
    // > ~450cyc loop body; depth 2 covers it)
    float em_p1 = emb[1 * NTAG + jj];   // t = 1
    float em_p2 = emb[2 * NTAG + jj];   // t = 2

    for (int t = 1; t < SEQ; ++t) {
        float em_j = em_p1;
        em_p1 = em_p2;
        int tn = (t + 2 < SEQ) ? (t + 2) : (SEQ - 1);
        em_p2 = emb[tn * NTAG + jj];

        // all 48 candidates kept in regs (static indices only -> no scratch)
        float cand[NTAG];
#pragma unroll
        for (int i = 0; i < NTAG; ++i)
            cand[i] = rl_f32(score, i) + trg[i];

        // exact max via max3 tree: 48 -> 16 -> 6 -> 2 -> 1  (24 ops)
        float l1[16];
#pragma unroll
        for (int k = 0; k < 16; ++k)
            l1[k] = max3(cand[3 * k], cand[3 * k + 1], cand[3 * k + 2]);
        float l2[6];
#pragma unroll
        for (int k = 0; k < 5; ++k)
            l2[k] = max3(l1[3 * k], l1[3 * k + 1], l1[3 * k + 2]);
        l2[5] = l1[15];
        float m0 = max3(l2[0], l2[1], l2[2]);
        float m1 = max3(l2[3], l2[4], l2[5]);
        float best = fmaxf(m0, m1);

        // first-max index: descending equality scan (ties -> smallest i),
        // bitwise-exact vs jnp.argmax since max is exact in fp
        int pi = 0;
#pragma unroll
        for (int i = NTAG - 1; i >= 0; --i)
            pi = (cand[i] == best) ? i : pi;

        if (j < NTAG) bpb[(size_t)t * NTAG + j] = (unsigned char)pi;
        score = best + em_j;
    }

    score += endt[jj];

    // final argmax across lanes 0..47 (uniform result in every lane)
    float m = rl_f32(score, 0); int tag = 0;
#pragma unroll
    for (int i = 1; i < NTAG; ++i) {
        float v = rl_f32(score, i);
        if (v > m) { m = v; tag = i; }
    }

    if (j == 0) obuf[SEQ - 1] = tag;

    // ---- backtrace: lane-parallel row loads (independent), 1 shfl per step ----
    // chunked by 16, double-buffered so next chunk's loads hide under shfl chain
    int cur[16], nxt[16];
    int t = SEQ - 1;
    int n = 16; // SEQ-1 = 1023 >= 16
#pragma unroll
    for (int k = 0; k < 16; ++k)
        cur[k] = (int)bpb[(size_t)(t - k) * NTAG + jj];

    while (t >= 1) {
        int t2 = t - n;
        int n2 = 0;
        if (t2 >= 1) {
            n2 = (t2 >= 16) ? 16 : t2;
#pragma unroll
            for (int k = 0; k < 16; ++k)
                if (k < n2) nxt[k] = (int)bpb[(size_t)(t2 - k) * NTAG + jj];
        }
#pragma unroll
        for (int k = 0; k < 16; ++k) {
            if (k < n) {
                tag = __shfl(cur[k], tag, 64);  // tag_{t-k-1} = row[tag_{t-k}]
                if (j == 0) obuf[t - k - 1] = tag;
            }
        }
#pragma unroll
        for (int k = 0; k < 16; ++k) cur[k] = nxt[k];
        t = t2; n = n2;
    }

    __syncthreads();

    // coalesced int32 dump of the batch's path
    int* outb = out + (size_t)b * SEQ;
#pragma unroll
    for (int t0 = 0; t0 < SEQ / 64; ++t0)
        outb[t0 * 64 + j] = obuf[t0 * 64 + j];
}

extern "C" void kernel_launch(void* const* d_in, const int* in_sizes, int n_in,
                              void* d_out, int out_size, void* d_ws, size_t ws_size,
                              hipStream_t stream) {
    const float* em    = (const float*)d_in[0];
    // d_in[1] = mask (int32), unused — matches reference
    const float* trans = (const float*)d_in[2];
    const float* start = (const float*)d_in[3];
    const float* endt  = (const float*)d_in[4];
    int* out = (int*)d_out;                     // reference output dtype is int32
    unsigned char* bpw = (unsigned char*)d_ws;  // needs B*S*T = 25,165,824 bytes

    crf_viterbi_kernel<<<NBATCH, 64, 0, stream>>>(em, trans, start, endt, out, bpw);
}